// Round 1
// baseline (909.392 us; speedup 1.0000x reference)
//
#include <hip/hip_runtime.h>

#define VN 50000
#define EN 800000
#define BN 4
#define CINN 64
#define COUTN 128
#define KN 4
#define FN 256  // BN * CINN

// ---------------------------------------------------------------------------
// row_ptr[v] = lower_bound(lap_rows, v): rows are sorted, so row v's edges are
// [row_ptr[v], row_ptr[v+1]).
// ---------------------------------------------------------------------------
__global__ __launch_bounds__(256) void build_row_ptr(const int* __restrict__ rows,
                                                     int* __restrict__ row_ptr) {
    int v = blockIdx.x * blockDim.x + threadIdx.x;
    if (v > VN) return;
    int lo = 0, hi = EN;
    while (lo < hi) {
        int mid = (lo + hi) >> 1;
        if (rows[mid] < v) lo = mid + 1; else hi = mid;
    }
    row_ptr[v] = lo;
}

// ---------------------------------------------------------------------------
// x is (256, V) row-major (f = b*CIN + i). Produce x0 = (V, 256) row-major.
// Classic 64x64 LDS tile transpose; both global read and write coalesced.
// ---------------------------------------------------------------------------
__global__ __launch_bounds__(256) void transpose_x(const float* __restrict__ x,
                                                   float* __restrict__ x0) {
    __shared__ float tile[64][65];
    int v0 = blockIdx.x * 64;
    int f0 = blockIdx.y * 64;
    int tx = threadIdx.x;  // 0..63
    int ty = threadIdx.y;  // 0..3
#pragma unroll
    for (int r = 0; r < 16; ++r) {
        int f = f0 + ty + r * 4;
        int v = v0 + tx;
        if (v < VN) tile[ty + r * 4][tx] = x[(size_t)f * VN + v];
    }
    __syncthreads();
#pragma unroll
    for (int r = 0; r < 16; ++r) {
        int v = v0 + ty + r * 4;
        int f = f0 + tx;
        if (v < VN) x0[(size_t)v * FN + f] = tile[tx][ty + r * 4];
    }
}

// ---------------------------------------------------------------------------
// out[v,:] = alpha * sum_{e in row v} vals[e]*z[cols[e],:]  +  beta * prev[v,:]
// One wave (64 lanes) per vertex; each lane owns 4 consecutive features
// (float4), so each edge gather is a coalesced 1KB row read.
// ---------------------------------------------------------------------------
__global__ __launch_bounds__(256) void spmm_cheb(float* __restrict__ out,
                                                 const float* __restrict__ z,
                                                 const float* __restrict__ prev,
                                                 const int* __restrict__ row_ptr,
                                                 const int* __restrict__ cols,
                                                 const float* __restrict__ vals,
                                                 float alpha, float beta) {
    int wave = (int)((blockIdx.x * blockDim.x + threadIdx.x) >> 6);
    int lane = threadIdx.x & 63;
    if (wave >= VN) return;
    int e0 = row_ptr[wave];
    int e1 = row_ptr[wave + 1];
    float4 acc = make_float4(0.f, 0.f, 0.f, 0.f);
    for (int e = e0; e < e1; ++e) {
        float val = vals[e];
        int c = cols[e];
        float4 zv = *reinterpret_cast<const float4*>(z + (size_t)c * FN + lane * 4);
        acc.x += val * zv.x;
        acc.y += val * zv.y;
        acc.z += val * zv.z;
        acc.w += val * zv.w;
    }
    float4 pv = *reinterpret_cast<const float4*>(prev + (size_t)wave * FN + lane * 4);
    float4 res;
    res.x = alpha * acc.x + beta * pv.x;
    res.y = alpha * acc.y + beta * pv.y;
    res.z = alpha * acc.z + beta * pv.z;
    res.w = alpha * acc.w + beta * pv.w;
    *reinterpret_cast<float4*>(out + (size_t)wave * FN + lane * 4) = res;
}

// ---------------------------------------------------------------------------
// out[b,o,v] = sum_{k,i} xk[v, b*64+i] * W[k,i,o] + bias[o]
// xk buffers are contiguous: xbase + k*V*256.
// Block: 64 vertices x 128 outputs, one b. Thread micro-tile: 4v x 8o.
// K-dim (k,i)=256 processed in 8 chunks of 32, staged through LDS.
// ---------------------------------------------------------------------------
__global__ __launch_bounds__(256) void cheb_gemm(float* __restrict__ out,
                                                 const float* __restrict__ xbase,
                                                 const float* __restrict__ weight,
                                                 const float* __restrict__ bias) {
    __shared__ float sx[64][36];   // [v_local][j], row stride 36 floats (144B, 16B-aligned)
    __shared__ float sw[32][132];  // [j][o], row stride 132 floats (528B, 16B-aligned)

    int b = blockIdx.y;
    int v0 = blockIdx.x * 64;
    int tid = threadIdx.x;
    int vG = tid & 15;   // v = v0 + vG*4 + vv   (lanes 0..15 consecutive v -> coalesced stores)
    int oG = tid >> 4;   // o = oG*8 + oo

    float acc[4][8];
#pragma unroll
    for (int a = 0; a < 4; ++a)
#pragma unroll
        for (int c = 0; c < 8; ++c) acc[a][c] = 0.f;

    for (int kc = 0; kc < 8; ++kc) {
        int kk0 = kc * 32;          // global K index of chunk start
        int k = kk0 >> 6;           // which Chebyshev term (32 | 64, so chunk stays in one k)
        int i0 = kk0 & 63;
        const float* xk = xbase + (size_t)k * VN * FN;

        __syncthreads();
        // stage x chunk: sx[vl][j] = xk[(v0+vl)*256 + b*64 + i0 + j]
#pragma unroll
        for (int p = 0; p < 8; ++p) {
            int idx = p * 256 + tid;
            int vl = idx >> 5;
            int j = idx & 31;
            int v = v0 + vl;
            sx[vl][j] = (v < VN) ? xk[(size_t)v * FN + b * CINN + i0 + j] : 0.f;
        }
        // stage w chunk: sw[j][o] = weight[(kk0+j)*128 + o]  (kk = k*64+i flat-indexes weight)
#pragma unroll
        for (int p = 0; p < 4; ++p) {
            int idx4 = p * 256 + tid;
            int j = idx4 >> 5;
            int o4 = idx4 & 31;
            float4 wv = *reinterpret_cast<const float4*>(weight + (size_t)(kk0 + j) * COUTN + o4 * 4);
            *reinterpret_cast<float4*>(&sw[j][o4 * 4]) = wv;
        }
        __syncthreads();

#pragma unroll
        for (int jq = 0; jq < 8; ++jq) {
            float4 xv[4];
#pragma unroll
            for (int vv = 0; vv < 4; ++vv)
                xv[vv] = *reinterpret_cast<const float4*>(&sx[vG * 4 + vv][jq * 4]);
#pragma unroll
            for (int jj = 0; jj < 4; ++jj) {
                float4 wa = *reinterpret_cast<const float4*>(&sw[jq * 4 + jj][oG * 8]);
                float4 wb = *reinterpret_cast<const float4*>(&sw[jq * 4 + jj][oG * 8 + 4]);
                float w8[8] = {wa.x, wa.y, wa.z, wa.w, wb.x, wb.y, wb.z, wb.w};
#pragma unroll
                for (int vv = 0; vv < 4; ++vv) {
                    float xval = (&xv[vv].x)[jj];
#pragma unroll
                    for (int oo = 0; oo < 8; ++oo)
                        acc[vv][oo] += xval * w8[oo];
                }
            }
        }
    }

    // epilogue: out[(b*128+o)*V + v], lanes 0..15 (vG) cover 64 consecutive v -> float4 stores
#pragma unroll
    for (int oo = 0; oo < 8; ++oo) {
        int o = oG * 8 + oo;
        float bv = bias[o];
        int v = v0 + vG * 4;
        size_t base = (size_t)(b * COUTN + o) * VN;
        if (v + 3 < VN) {
            float4 st = make_float4(acc[0][oo] + bv, acc[1][oo] + bv,
                                    acc[2][oo] + bv, acc[3][oo] + bv);
            *reinterpret_cast<float4*>(out + base + v) = st;
        } else {
#pragma unroll
            for (int vv = 0; vv < 4; ++vv)
                if (v + vv < VN) out[base + v + vv] = acc[vv][oo] + bv;
        }
    }
}

// ---------------------------------------------------------------------------
extern "C" void kernel_launch(void* const* d_in, const int* in_sizes, int n_in,
                              void* d_out, int out_size, void* d_ws, size_t ws_size,
                              hipStream_t stream) {
    const float* x        = (const float*)d_in[0];
    const int*   lap_rows = (const int*)d_in[1];
    const int*   lap_cols = (const int*)d_in[2];
    const float* lap_vals = (const float*)d_in[3];
    const float* weight   = (const float*)d_in[4];
    const float* bias     = (const float*)d_in[5];
    float* out = (float*)d_out;

    float* ws = (float*)d_ws;
    float* x0 = ws;                               // (V, 256) each, contiguous x0..x3
    float* x1 = x0 + (size_t)VN * FN;
    float* x2 = x1 + (size_t)VN * FN;
    float* x3 = x2 + (size_t)VN * FN;
    int* row_ptr = (int*)(x3 + (size_t)VN * FN);  // V+1 ints

    build_row_ptr<<<(VN + 1 + 255) / 256, 256, 0, stream>>>(lap_rows, row_ptr);
    transpose_x<<<dim3((VN + 63) / 64, FN / 64), dim3(64, 4), 0, stream>>>(x, x0);
    // x1 = L x0
    spmm_cheb<<<(VN + 3) / 4, 256, 0, stream>>>(x1, x0, x0, row_ptr, lap_cols, lap_vals, 1.f, 0.f);
    // x2 = 2 L x1 - x0
    spmm_cheb<<<(VN + 3) / 4, 256, 0, stream>>>(x2, x1, x0, row_ptr, lap_cols, lap_vals, 2.f, -1.f);
    // x3 = 2 L x2 - x1
    spmm_cheb<<<(VN + 3) / 4, 256, 0, stream>>>(x3, x2, x1, row_ptr, lap_cols, lap_vals, 2.f, -1.f);
    // out = sum_k xk @ Wk + bias
    cheb_gemm<<<dim3((VN + 63) / 64, BN), 256, 0, stream>>>(out, x0, weight, bias);
}

// Round 2
// 598.375 us; speedup vs baseline: 1.5198x; 1.5198x over previous
//
#include <hip/hip_runtime.h>
#include <hip/hip_bf16.h>

#define VN 50000
#define EN 800000
#define BN 4
#define CINN 64
#define COUTN 128
#define KN 4
#define FN 256  // BN * CINN

typedef __attribute__((ext_vector_type(8))) short short8;
typedef __attribute__((ext_vector_type(4))) float floatx4;

// ---------------------------------------------------------------------------
// row_ptr[v] = lower_bound(lap_rows, v)
// ---------------------------------------------------------------------------
__global__ __launch_bounds__(256) void build_row_ptr(const int* __restrict__ rows,
                                                     int* __restrict__ row_ptr) {
    int v = blockIdx.x * blockDim.x + threadIdx.x;
    if (v > VN) return;
    int lo = 0, hi = EN;
    while (lo < hi) {
        int mid = (lo + hi) >> 1;
        if (rows[mid] < v) lo = mid + 1; else hi = mid;
    }
    row_ptr[v] = lo;
}

// ---------------------------------------------------------------------------
// x (256, V) -> x0 (V, 256), 64x64 LDS tile transpose.
// ---------------------------------------------------------------------------
__global__ __launch_bounds__(256) void transpose_x(const float* __restrict__ x,
                                                   float* __restrict__ x0) {
    __shared__ float tile[64][65];
    int v0 = blockIdx.x * 64;
    int f0 = blockIdx.y * 64;
    int tx = threadIdx.x;
    int ty = threadIdx.y;
#pragma unroll
    for (int r = 0; r < 16; ++r) {
        int f = f0 + ty + r * 4;
        int v = v0 + tx;
        if (v < VN) tile[ty + r * 4][tx] = x[(size_t)f * VN + v];
    }
    __syncthreads();
#pragma unroll
    for (int r = 0; r < 16; ++r) {
        int v = v0 + ty + r * 4;
        int f = f0 + tx;
        if (v < VN) x0[(size_t)v * FN + f] = tile[tx][ty + r * 4];
    }
}

// ---------------------------------------------------------------------------
// wT[o][k*64+i] = bf16(weight[k][i][o])   -- (128, 256) bf16, A-operand source
// ---------------------------------------------------------------------------
__global__ __launch_bounds__(256) void prep_wT(const float* __restrict__ w,
                                               ushort* __restrict__ wT) {
    int idx = blockIdx.x * 256 + threadIdx.x;  // 32768 total
    int o = idx >> 8;
    int kk = idx & 255;
    __hip_bfloat16 h = __float2bfloat16(w[(size_t)kk * COUTN + o]);
    wT[idx] = *reinterpret_cast<ushort*>(&h);
}

// ---------------------------------------------------------------------------
// out[v,:] = alpha * sum_e vals[e]*z[cols[e],:] + beta * prev[v,:]
// One wave per vertex, lane owns float4 of features; 2-deep edge pipeline.
// ---------------------------------------------------------------------------
__global__ __launch_bounds__(256) void spmm_cheb(float* __restrict__ out,
                                                 const float* __restrict__ z,
                                                 const float* __restrict__ prev,
                                                 const int* __restrict__ row_ptr,
                                                 const int* __restrict__ cols,
                                                 const float* __restrict__ vals,
                                                 float alpha, float beta) {
    int wave = (int)((blockIdx.x * blockDim.x + threadIdx.x) >> 6);
    int lane = threadIdx.x & 63;
    if (wave >= VN) return;
    int e0 = row_ptr[wave];
    int e1 = row_ptr[wave + 1];
    float4 acc0 = make_float4(0.f, 0.f, 0.f, 0.f);
    float4 acc1 = make_float4(0.f, 0.f, 0.f, 0.f);
    int e = e0;
    for (; e + 1 < e1; e += 2) {
        int c0 = cols[e], c1 = cols[e + 1];
        float w0 = vals[e], w1 = vals[e + 1];
        float4 z0 = *reinterpret_cast<const float4*>(z + (size_t)c0 * FN + lane * 4);
        float4 z1 = *reinterpret_cast<const float4*>(z + (size_t)c1 * FN + lane * 4);
        acc0.x += w0 * z0.x; acc0.y += w0 * z0.y; acc0.z += w0 * z0.z; acc0.w += w0 * z0.w;
        acc1.x += w1 * z1.x; acc1.y += w1 * z1.y; acc1.z += w1 * z1.z; acc1.w += w1 * z1.w;
    }
    if (e < e1) {
        int c0 = cols[e];
        float w0 = vals[e];
        float4 z0 = *reinterpret_cast<const float4*>(z + (size_t)c0 * FN + lane * 4);
        acc0.x += w0 * z0.x; acc0.y += w0 * z0.y; acc0.z += w0 * z0.z; acc0.w += w0 * z0.w;
    }
    acc0.x += acc1.x; acc0.y += acc1.y; acc0.z += acc1.z; acc0.w += acc1.w;
    float4 pv = *reinterpret_cast<const float4*>(prev + (size_t)wave * FN + lane * 4);
    float4 res;
    res.x = alpha * acc0.x + beta * pv.x;
    res.y = alpha * acc0.y + beta * pv.y;
    res.z = alpha * acc0.z + beta * pv.z;
    res.w = alpha * acc0.w + beta * pv.w;
    *reinterpret_cast<float4*>(out + (size_t)wave * FN + lane * 4) = res;
}

// ---------------------------------------------------------------------------
// MFMA GEMM:  out[b,o,v] = sum_{kk=0..255} wT[o][kk] * xk(v, b-slice)[kk] + bias[o]
// A-operand = wT (M=o=128), B-operand = x rows (N=v, 128/block). K chunk = 64
// (= one Chebyshev term). LDS tiles [row][64 bf16] with 16B-granule XOR swizzle
// (pos = g ^ (row&7)); staging writes are LDS-linear per thread.
// D layout: col(lane&15)=v -> contiguous 64B store segments per quad.
// ---------------------------------------------------------------------------
__global__ __launch_bounds__(256) void cheb_gemm_mfma(float* __restrict__ out,
                                                      const float* __restrict__ xbase,
                                                      const ushort* __restrict__ wT,
                                                      const float* __restrict__ bias) {
    __shared__ __align__(16) short lsA[128 * 64];  // [o][64 bf16], granule-swizzled
    __shared__ __align__(16) short lsB[128 * 64];  // [v][64 bf16], granule-swizzled

    int b = blockIdx.y;
    int v0 = blockIdx.x * 128;
    int tid = threadIdx.x;
    int lane = tid & 63;
    int w = tid >> 6;
    int mw = w & 1;        // o-half of block tile
    int nw = w >> 1;       // v-half of block tile
    int ln = lane & 15;
    int quad = lane >> 4;

    int srow = tid >> 1;       // staging row 0..127
    int posBase = (tid & 1) * 4;

    floatx4 acc[4][4];
#pragma unroll
    for (int mi = 0; mi < 4; ++mi)
#pragma unroll
        for (int ni = 0; ni < 4; ++ni) acc[mi][ni] = (floatx4){0.f, 0.f, 0.f, 0.f};

    for (int kc = 0; kc < 4; ++kc) {
        __syncthreads();
        // ---- stage A: wT rows (o), this chunk's 64 bf16 ----
#pragma unroll
        for (int j = 0; j < 4; ++j) {
            int pos = posBase + j;
            int g = pos ^ (srow & 7);
            uint4 val = *reinterpret_cast<const uint4*>(wT + (size_t)srow * 256 + kc * 64 + g * 8);
            *reinterpret_cast<uint4*>(&lsA[(srow * 8 + pos) * 8]) = val;
        }
        // ---- stage B: x_kc fp32 -> bf16 ----
        {
            const float* xk = xbase + (size_t)kc * VN * FN;
            int v = v0 + srow;
            bool ok = (v < VN);
            const float* src = xk + (size_t)v * FN + b * CINN;
#pragma unroll
            for (int j = 0; j < 4; ++j) {
                int pos = posBase + j;
                int g = pos ^ (srow & 7);
                float4 f0, f1;
                if (ok) {
                    f0 = *reinterpret_cast<const float4*>(src + g * 8);
                    f1 = *reinterpret_cast<const float4*>(src + g * 8 + 4);
                } else {
                    f0 = make_float4(0.f, 0.f, 0.f, 0.f);
                    f1 = f0;
                }
                short8 pk;
                __hip_bfloat16 h;
                h = __float2bfloat16(f0.x); pk[0] = *reinterpret_cast<short*>(&h);
                h = __float2bfloat16(f0.y); pk[1] = *reinterpret_cast<short*>(&h);
                h = __float2bfloat16(f0.z); pk[2] = *reinterpret_cast<short*>(&h);
                h = __float2bfloat16(f0.w); pk[3] = *reinterpret_cast<short*>(&h);
                h = __float2bfloat16(f1.x); pk[4] = *reinterpret_cast<short*>(&h);
                h = __float2bfloat16(f1.y); pk[5] = *reinterpret_cast<short*>(&h);
                h = __float2bfloat16(f1.z); pk[6] = *reinterpret_cast<short*>(&h);
                h = __float2bfloat16(f1.w); pk[7] = *reinterpret_cast<short*>(&h);
                *reinterpret_cast<short8*>(&lsB[(srow * 8 + pos) * 8]) = pk;
            }
        }
        __syncthreads();

        // ---- MFMA: 2 k-steps of 32 ----
#pragma unroll
        for (int s = 0; s < 2; ++s) {
            short8 afr[4], bfr[4];
#pragma unroll
            for (int mi = 0; mi < 4; ++mi) {
                int r = mw * 64 + mi * 16 + ln;
                int pos = (s * 4 + quad) ^ (r & 7);
                afr[mi] = *reinterpret_cast<const short8*>(&lsA[(r * 8 + pos) * 8]);
            }
#pragma unroll
            for (int ni = 0; ni < 4; ++ni) {
                int r = nw * 64 + ni * 16 + ln;
                int pos = (s * 4 + quad) ^ (r & 7);
                bfr[ni] = *reinterpret_cast<const short8*>(&lsB[(r * 8 + pos) * 8]);
            }
#pragma unroll
            for (int mi = 0; mi < 4; ++mi)
#pragma unroll
                for (int ni = 0; ni < 4; ++ni)
                    acc[mi][ni] = __builtin_amdgcn_mfma_f32_16x16x32_bf16(
                        afr[mi], bfr[ni], acc[mi][ni], 0, 0, 0);
        }
    }

    // ---- epilogue: D col(ln)=v, row(quad*4+r)=o ----
#pragma unroll
    for (int mi = 0; mi < 4; ++mi) {
#pragma unroll
        for (int r = 0; r < 4; ++r) {
            int o = mw * 64 + mi * 16 + quad * 4 + r;
            float bv = bias[o];
            size_t obase = (size_t)(b * COUTN + o) * VN;
#pragma unroll
            for (int ni = 0; ni < 4; ++ni) {
                int v = v0 + nw * 64 + ni * 16 + ln;
                if (v < VN) out[obase + v] = acc[mi][ni][r] + bv;
            }
        }
    }
}

// ---------------------------------------------------------------------------
extern "C" void kernel_launch(void* const* d_in, const int* in_sizes, int n_in,
                              void* d_out, int out_size, void* d_ws, size_t ws_size,
                              hipStream_t stream) {
    const float* x        = (const float*)d_in[0];
    const int*   lap_rows = (const int*)d_in[1];
    const int*   lap_cols = (const int*)d_in[2];
    const float* lap_vals = (const float*)d_in[3];
    const float* weight   = (const float*)d_in[4];
    const float* bias     = (const float*)d_in[5];
    float* out = (float*)d_out;

    char* ws = (char*)d_ws;
    float* x0 = (float*)ws;                          // 4 x (V,256) fp32, contiguous
    float* x1 = x0 + (size_t)VN * FN;
    float* x2 = x1 + (size_t)VN * FN;
    float* x3 = x2 + (size_t)VN * FN;
    size_t xbytes = (size_t)4 * VN * FN * sizeof(float);
    int* row_ptr = (int*)(ws + xbytes);              // V+1 ints
    size_t rp_end = xbytes + (size_t)(VN + 1) * sizeof(int);
    rp_end = (rp_end + 15) & ~(size_t)15;            // 16B align
    ushort* wT = (ushort*)(ws + rp_end);             // (128,256) bf16

    build_row_ptr<<<(VN + 1 + 255) / 256, 256, 0, stream>>>(lap_rows, row_ptr);
    prep_wT<<<128, 256, 0, stream>>>(weight, wT);
    transpose_x<<<dim3((VN + 63) / 64, FN / 64), dim3(64, 4), 0, stream>>>(x, x0);
    // x1 = L x0
    spmm_cheb<<<(VN + 3) / 4, 256, 0, stream>>>(x1, x0, x0, row_ptr, lap_cols, lap_vals, 1.f, 0.f);
    // x2 = 2 L x1 - x0
    spmm_cheb<<<(VN + 3) / 4, 256, 0, stream>>>(x2, x1, x0, row_ptr, lap_cols, lap_vals, 2.f, -1.f);
    // x3 = 2 L x2 - x1
    spmm_cheb<<<(VN + 3) / 4, 256, 0, stream>>>(x3, x2, x1, row_ptr, lap_cols, lap_vals, 2.f, -1.f);
    // out = sum_k xk @ Wk + bias  (MFMA)
    cheb_gemm_mfma<<<dim3((VN + 127) / 128, BN), 256, 0, stream>>>(out, x0, wT, bias);
}

// Round 3
// 388.721 us; speedup vs baseline: 2.3394x; 1.5393x over previous
//
#include <hip/hip_runtime.h>
#include <hip/hip_bf16.h>

#define VN 50000
#define EN 800000
#define BN 4
#define CINN 64
#define COUTN 128
#define KN 4
#define FN 256  // BN * CINN

typedef __attribute__((ext_vector_type(8))) short short8;
typedef __attribute__((ext_vector_type(8))) unsigned short ushort8;
typedef __attribute__((ext_vector_type(4))) float floatx4;

__device__ __forceinline__ float bf2f(unsigned short u) {
    union { unsigned int i; float f; } c;
    c.i = ((unsigned int)u) << 16;
    return c.f;
}
__device__ __forceinline__ unsigned short f2bf(float f) {
    __hip_bfloat16 h = __float2bfloat16(f);
    return *reinterpret_cast<unsigned short*>(&h);
}

// ---------------------------------------------------------------------------
// row_ptr[v] = lower_bound(lap_rows, v)
// ---------------------------------------------------------------------------
__global__ __launch_bounds__(256) void build_row_ptr(const int* __restrict__ rows,
                                                     int* __restrict__ row_ptr) {
    int v = blockIdx.x * blockDim.x + threadIdx.x;
    if (v > VN) return;
    int lo = 0, hi = EN;
    while (lo < hi) {
        int mid = (lo + hi) >> 1;
        if (rows[mid] < v) lo = mid + 1; else hi = mid;
    }
    row_ptr[v] = lo;
}

// ---------------------------------------------------------------------------
// x (256, V) fp32 -> x0 (V, 256) bf16, 64x64 LDS tile transpose.
// ---------------------------------------------------------------------------
__global__ __launch_bounds__(256) void transpose_x_bf16(const float* __restrict__ x,
                                                        ushort* __restrict__ x0) {
    __shared__ float tile[64][65];
    int v0 = blockIdx.x * 64;
    int f0 = blockIdx.y * 64;
    int tx = threadIdx.x;
    int ty = threadIdx.y;
#pragma unroll
    for (int r = 0; r < 16; ++r) {
        int f = f0 + ty + r * 4;
        int v = v0 + tx;
        if (v < VN) tile[ty + r * 4][tx] = x[(size_t)f * VN + v];
    }
    __syncthreads();
#pragma unroll
    for (int r = 0; r < 16; ++r) {
        int v = v0 + ty + r * 4;
        int f = f0 + tx;
        if (v < VN) x0[(size_t)v * FN + f] = f2bf(tile[tx][ty + r * 4]);
    }
}

// ---------------------------------------------------------------------------
// wT[o][k*64+i] = bf16(weight[k][i][o])   -- (128, 256) bf16, A-operand source
// ---------------------------------------------------------------------------
__global__ __launch_bounds__(256) void prep_wT(const float* __restrict__ w,
                                               ushort* __restrict__ wT) {
    int idx = blockIdx.x * 256 + threadIdx.x;  // 32768 total
    int o = idx >> 8;
    int kk = idx & 255;
    wT[idx] = f2bf(w[(size_t)kk * COUTN + o]);
}

// ---------------------------------------------------------------------------
// bf16 SpMM: out[v,:] = alpha * sum_e vals[e]*z[cols[e],:] + beta * prev[v,:]
// One wave per vertex. Half-wave edge split: lanes 0-31 even edges, 32-63 odd.
// Each lane owns 8 bf16 features (16B ushort8 gather). fp32 accumulation,
// final cross-half butterfly merge, bf16 store by lanes 0-31.
// ---------------------------------------------------------------------------
__global__ __launch_bounds__(256) void spmm_cheb_bf16(ushort* __restrict__ out,
                                                      const ushort* __restrict__ z,
                                                      const ushort* __restrict__ prev,
                                                      const int* __restrict__ row_ptr,
                                                      const int* __restrict__ cols,
                                                      const float* __restrict__ vals,
                                                      float alpha, float beta) {
    int row = (int)((blockIdx.x * blockDim.x + threadIdx.x) >> 6);
    int lane = threadIdx.x & 63;
    if (row >= VN) return;
    int e0 = row_ptr[row];
    int e1 = row_ptr[row + 1];
    int half = lane >> 5;        // 0: even edges, 1: odd edges
    int fl = (lane & 31) * 8;    // 8 features per lane

    float acc0[8], acc1[8];
#pragma unroll
    for (int j = 0; j < 8; ++j) { acc0[j] = 0.f; acc1[j] = 0.f; }

    int e = e0 + half;
    // 2-deep pipeline within each half (stride 4 over edges)
    for (; e + 2 < e1; e += 4) {
        int c0 = cols[e], c1 = cols[e + 2];
        float w0 = vals[e], w1 = vals[e + 2];
        ushort8 z0 = *reinterpret_cast<const ushort8*>(z + (size_t)c0 * FN + fl);
        ushort8 z1 = *reinterpret_cast<const ushort8*>(z + (size_t)c1 * FN + fl);
#pragma unroll
        for (int j = 0; j < 8; ++j) acc0[j] += w0 * bf2f(z0[j]);
#pragma unroll
        for (int j = 0; j < 8; ++j) acc1[j] += w1 * bf2f(z1[j]);
    }
    for (; e < e1; e += 2) {
        int c0 = cols[e];
        float w0 = vals[e];
        ushort8 z0 = *reinterpret_cast<const ushort8*>(z + (size_t)c0 * FN + fl);
#pragma unroll
        for (int j = 0; j < 8; ++j) acc0[j] += w0 * bf2f(z0[j]);
    }
#pragma unroll
    for (int j = 0; j < 8; ++j) acc0[j] += acc1[j];
    // butterfly: merge the two halves (both end up with the full sum)
#pragma unroll
    for (int j = 0; j < 8; ++j) acc0[j] += __shfl(acc0[j], lane ^ 32);

    if (half == 0) {
        ushort8 pv = *reinterpret_cast<const ushort8*>(prev + (size_t)row * FN + fl);
        ushort8 res;
#pragma unroll
        for (int j = 0; j < 8; ++j)
            res[j] = f2bf(alpha * acc0[j] + beta * bf2f(pv[j]));
        *reinterpret_cast<ushort8*>(out + (size_t)row * FN + fl) = res;
    }
}

// ---------------------------------------------------------------------------
// MFMA GEMM:  out[b,o,v] = sum_{kk=0..255} wT[o][kk] * xk(v, b-slice)[kk] + bias[o]
// A = wT (M=o=128), B = x rows (N=v, 128/block), all bf16 in global already.
// K chunk = 64 (one Chebyshev term). LDS [row][64 bf16], 16B-granule XOR
// swizzle (pos = g ^ (row&7)). D: col(lane&15)=v -> coalesced stores.
// ---------------------------------------------------------------------------
__global__ __launch_bounds__(256) void cheb_gemm_mfma(float* __restrict__ out,
                                                      const ushort* __restrict__ xbase,
                                                      const ushort* __restrict__ wT,
                                                      const float* __restrict__ bias) {
    __shared__ __align__(16) short lsA[128 * 64];
    __shared__ __align__(16) short lsB[128 * 64];

    int b = blockIdx.y;
    int v0 = blockIdx.x * 128;
    int tid = threadIdx.x;
    int lane = tid & 63;
    int w = tid >> 6;
    int mw = w & 1;
    int nw = w >> 1;
    int ln = lane & 15;
    int quad = lane >> 4;

    int srow = tid >> 1;
    int posBase = (tid & 1) * 4;

    floatx4 acc[4][4];
#pragma unroll
    for (int mi = 0; mi < 4; ++mi)
#pragma unroll
        for (int ni = 0; ni < 4; ++ni) acc[mi][ni] = (floatx4){0.f, 0.f, 0.f, 0.f};

    for (int kc = 0; kc < 4; ++kc) {
        __syncthreads();
        // stage A: wT rows (o)
#pragma unroll
        for (int j = 0; j < 4; ++j) {
            int pos = posBase + j;
            int g = pos ^ (srow & 7);
            uint4 val = *reinterpret_cast<const uint4*>(wT + (size_t)srow * 256 + kc * 64 + g * 8);
            *reinterpret_cast<uint4*>(&lsA[(srow * 8 + pos) * 8]) = val;
        }
        // stage B: xk bf16 direct copy
        {
            const ushort* xk = xbase + (size_t)kc * VN * FN;
            int v = v0 + srow;
            bool ok = (v < VN);
            const ushort* src = xk + (size_t)v * FN + b * CINN;
#pragma unroll
            for (int j = 0; j < 4; ++j) {
                int pos = posBase + j;
                int g = pos ^ (srow & 7);
                uint4 val;
                if (ok) val = *reinterpret_cast<const uint4*>(src + g * 8);
                else    val = make_uint4(0u, 0u, 0u, 0u);
                *reinterpret_cast<uint4*>(&lsB[(srow * 8 + pos) * 8]) = val;
            }
        }
        __syncthreads();

#pragma unroll
        for (int s = 0; s < 2; ++s) {
            short8 afr[4], bfr[4];
#pragma unroll
            for (int mi = 0; mi < 4; ++mi) {
                int r = mw * 64 + mi * 16 + ln;
                int pos = (s * 4 + quad) ^ (r & 7);
                afr[mi] = *reinterpret_cast<const short8*>(&lsA[(r * 8 + pos) * 8]);
            }
#pragma unroll
            for (int ni = 0; ni < 4; ++ni) {
                int r = nw * 64 + ni * 16 + ln;
                int pos = (s * 4 + quad) ^ (r & 7);
                bfr[ni] = *reinterpret_cast<const short8*>(&lsB[(r * 8 + pos) * 8]);
            }
#pragma unroll
            for (int mi = 0; mi < 4; ++mi)
#pragma unroll
                for (int ni = 0; ni < 4; ++ni)
                    acc[mi][ni] = __builtin_amdgcn_mfma_f32_16x16x32_bf16(
                        afr[mi], bfr[ni], acc[mi][ni], 0, 0, 0);
        }
    }

#pragma unroll
    for (int mi = 0; mi < 4; ++mi) {
#pragma unroll
        for (int r = 0; r < 4; ++r) {
            int o = mw * 64 + mi * 16 + quad * 4 + r;
            float bv = bias[o];
            size_t obase = (size_t)(b * COUTN + o) * VN;
#pragma unroll
            for (int ni = 0; ni < 4; ++ni) {
                int v = v0 + nw * 64 + ni * 16 + ln;
                if (v < VN) out[obase + v] = acc[mi][ni][r] + bv;
            }
        }
    }
}

// ---------------------------------------------------------------------------
extern "C" void kernel_launch(void* const* d_in, const int* in_sizes, int n_in,
                              void* d_out, int out_size, void* d_ws, size_t ws_size,
                              hipStream_t stream) {
    const float* x        = (const float*)d_in[0];
    const int*   lap_rows = (const int*)d_in[1];
    const int*   lap_cols = (const int*)d_in[2];
    const float* lap_vals = (const float*)d_in[3];
    const float* weight   = (const float*)d_in[4];
    const float* bias     = (const float*)d_in[5];
    float* out = (float*)d_out;

    char* ws = (char*)d_ws;
    ushort* x0 = (ushort*)ws;                        // 4 x (V,256) bf16, contiguous
    ushort* x1 = x0 + (size_t)VN * FN;
    ushort* x2 = x1 + (size_t)VN * FN;
    ushort* x3 = x2 + (size_t)VN * FN;
    size_t xbytes = (size_t)4 * VN * FN * sizeof(ushort);
    int* row_ptr = (int*)(ws + xbytes);              // V+1 ints
    size_t rp_end = xbytes + (size_t)(VN + 1) * sizeof(int);
    rp_end = (rp_end + 15) & ~(size_t)15;            // 16B align
    ushort* wT = (ushort*)(ws + rp_end);             // (128,256) bf16

    build_row_ptr<<<(VN + 1 + 255) / 256, 256, 0, stream>>>(lap_rows, row_ptr);
    prep_wT<<<128, 256, 0, stream>>>(weight, wT);
    transpose_x_bf16<<<dim3((VN + 63) / 64, FN / 64), dim3(64, 4), 0, stream>>>(x, x0);
    // x1 = L x0
    spmm_cheb_bf16<<<(VN + 3) / 4, 256, 0, stream>>>(x1, x0, x0, row_ptr, lap_cols, lap_vals, 1.f, 0.f);
    // x2 = 2 L x1 - x0
    spmm_cheb_bf16<<<(VN + 3) / 4, 256, 0, stream>>>(x2, x1, x0, row_ptr, lap_cols, lap_vals, 2.f, -1.f);
    // x3 = 2 L x2 - x1
    spmm_cheb_bf16<<<(VN + 3) / 4, 256, 0, stream>>>(x3, x2, x1, row_ptr, lap_cols, lap_vals, 2.f, -1.f);
    // out = sum_k xk @ Wk + bias  (MFMA)
    cheb_gemm_mfma<<<dim3((VN + 127) / 128, BN), 256, 0, stream>>>(out, x0, wT, bias);
}

// Round 4
// 373.008 us; speedup vs baseline: 2.4380x; 1.0421x over previous
//
#include <hip/hip_runtime.h>
#include <hip/hip_bf16.h>

#define VN 50000
#define EN 800000
#define BN 4
#define CINN 64
#define COUTN 128
#define KN 4
#define FN 256  // BN * CINN

typedef __attribute__((ext_vector_type(8))) short short8;
typedef __attribute__((ext_vector_type(8))) unsigned short ushort8;
typedef __attribute__((ext_vector_type(4))) float floatx4;

__device__ __forceinline__ float bf2f(unsigned short u) {
    union { unsigned int i; float f; } c;
    c.i = ((unsigned int)u) << 16;
    return c.f;
}
__device__ __forceinline__ unsigned short f2bf(float f) {
    __hip_bfloat16 h = __float2bfloat16(f);
    return *reinterpret_cast<unsigned short*>(&h);
}

#define RP_BLOCKS 196    // (VN+1+255)/256
#define WT_BLOCKS 128    // 128*256/256
#define TP_BX 782        // (VN+63)/64
#define TP_BLOCKS (TP_BX * 4)

// ---------------------------------------------------------------------------
// Fused setup: [0,RP) row_ptr lower_bound; [RP,RP+WT) wT transpose+bf16;
// rest: 64x64 x-transpose fp32->bf16. All block-uniform branches.
// ---------------------------------------------------------------------------
__global__ __launch_bounds__(256) void setup_fused(const int* __restrict__ rows,
                                                   int* __restrict__ row_ptr,
                                                   const float* __restrict__ w,
                                                   ushort* __restrict__ wT,
                                                   const float* __restrict__ x,
                                                   ushort* __restrict__ x0) {
    __shared__ float tile[64][65];
    int blk = blockIdx.x;
    int tid = threadIdx.x;
    if (blk < RP_BLOCKS) {
        int v = blk * 256 + tid;
        if (v > VN) return;
        int lo = 0, hi = EN;
        while (lo < hi) {
            int mid = (lo + hi) >> 1;
            if (rows[mid] < v) lo = mid + 1; else hi = mid;
        }
        row_ptr[v] = lo;
        return;
    }
    if (blk < RP_BLOCKS + WT_BLOCKS) {
        int idx = (blk - RP_BLOCKS) * 256 + tid;  // 32768 total
        int o = idx >> 8;
        int kk = idx & 255;
        wT[idx] = f2bf(w[(size_t)kk * COUTN + o]);
        return;
    }
    int t = blk - RP_BLOCKS - WT_BLOCKS;
    int v0 = (t % TP_BX) * 64;
    int f0 = (t / TP_BX) * 64;
    int tx = tid & 63;
    int ty = tid >> 6;
#pragma unroll
    for (int r = 0; r < 16; ++r) {
        int f = f0 + ty + r * 4;
        int v = v0 + tx;
        if (v < VN) tile[ty + r * 4][tx] = x[(size_t)f * VN + v];
    }
    __syncthreads();
#pragma unroll
    for (int r = 0; r < 16; ++r) {
        int v = v0 + ty + r * 4;
        int f = f0 + tx;
        if (v < VN) x0[(size_t)v * FN + f] = f2bf(tile[tx][ty + r * 4]);
    }
}

// ---------------------------------------------------------------------------
// bf16 SpMM: out[v,:] = alpha * sum_e vals[e]*z[cols[e],:] + beta * prev[v,:]
// One wave per vertex; lanes 0-31 even edges, 32-63 odd. Each lane owns 8 bf16
// features (16B gather). 4-deep gather pipeline per half (stride 8 over edges)
// -> 4 gathers in flight per wave. fp32 accum, butterfly merge, bf16 store.
// ---------------------------------------------------------------------------
__global__ __launch_bounds__(256) void spmm_cheb_bf16(ushort* __restrict__ out,
                                                      const ushort* __restrict__ z,
                                                      const ushort* __restrict__ prev,
                                                      const int* __restrict__ row_ptr,
                                                      const int* __restrict__ cols,
                                                      const float* __restrict__ vals,
                                                      float alpha, float beta) {
    int row = (int)((blockIdx.x * blockDim.x + threadIdx.x) >> 6);
    int lane = threadIdx.x & 63;
    if (row >= VN) return;
    int e0 = row_ptr[row];
    int e1 = row_ptr[row + 1];
    int half = lane >> 5;        // 0: even edges, 1: odd edges
    int fl = (lane & 31) * 8;    // 8 features per lane

    float acc0[8], acc1[8];
#pragma unroll
    for (int j = 0; j < 8; ++j) { acc0[j] = 0.f; acc1[j] = 0.f; }

    int e = e0 + half;
    // 4-deep main loop: 4 gathers in flight per half
    for (; e + 6 < e1; e += 8) {
        int c0 = cols[e], c1 = cols[e + 2], c2 = cols[e + 4], c3 = cols[e + 6];
        float w0 = vals[e], w1 = vals[e + 2], w2 = vals[e + 4], w3 = vals[e + 6];
        ushort8 z0 = *reinterpret_cast<const ushort8*>(z + (size_t)c0 * FN + fl);
        ushort8 z1 = *reinterpret_cast<const ushort8*>(z + (size_t)c1 * FN + fl);
        ushort8 z2 = *reinterpret_cast<const ushort8*>(z + (size_t)c2 * FN + fl);
        ushort8 z3 = *reinterpret_cast<const ushort8*>(z + (size_t)c3 * FN + fl);
#pragma unroll
        for (int j = 0; j < 8; ++j) acc0[j] += w0 * bf2f(z0[j]);
#pragma unroll
        for (int j = 0; j < 8; ++j) acc1[j] += w1 * bf2f(z1[j]);
#pragma unroll
        for (int j = 0; j < 8; ++j) acc0[j] += w2 * bf2f(z2[j]);
#pragma unroll
        for (int j = 0; j < 8; ++j) acc1[j] += w3 * bf2f(z3[j]);
    }
    // 2-deep remainder
    for (; e + 2 < e1; e += 4) {
        int c0 = cols[e], c1 = cols[e + 2];
        float w0 = vals[e], w1 = vals[e + 2];
        ushort8 z0 = *reinterpret_cast<const ushort8*>(z + (size_t)c0 * FN + fl);
        ushort8 z1 = *reinterpret_cast<const ushort8*>(z + (size_t)c1 * FN + fl);
#pragma unroll
        for (int j = 0; j < 8; ++j) acc0[j] += w0 * bf2f(z0[j]);
#pragma unroll
        for (int j = 0; j < 8; ++j) acc1[j] += w1 * bf2f(z1[j]);
    }
    for (; e < e1; e += 2) {
        int c0 = cols[e];
        float w0 = vals[e];
        ushort8 z0 = *reinterpret_cast<const ushort8*>(z + (size_t)c0 * FN + fl);
#pragma unroll
        for (int j = 0; j < 8; ++j) acc0[j] += w0 * bf2f(z0[j]);
    }
#pragma unroll
    for (int j = 0; j < 8; ++j) acc0[j] += acc1[j];
    // butterfly: merge even/odd halves
#pragma unroll
    for (int j = 0; j < 8; ++j) acc0[j] += __shfl(acc0[j], lane ^ 32);

    if (half == 0) {
        ushort8 pv = *reinterpret_cast<const ushort8*>(prev + (size_t)row * FN + fl);
        ushort8 res;
#pragma unroll
        for (int j = 0; j < 8; ++j)
            res[j] = f2bf(alpha * acc0[j] + beta * bf2f(pv[j]));
        *reinterpret_cast<ushort8*>(out + (size_t)row * FN + fl) = res;
    }
}

// ---------------------------------------------------------------------------
// MFMA GEMM:  out[b,o,v] = sum_{kk=0..255} wT[o][kk] * xk(v, b-slice)[kk] + bias[o]
// A = wT (M=o=128), B = x rows (N=v, 128/block), bf16. K chunk = 64 (one
// Chebyshev term). LDS [row][64 bf16], 16B-granule XOR swizzle.
// D: col(lane&15)=v -> coalesced stores.
// ---------------------------------------------------------------------------
__global__ __launch_bounds__(256) void cheb_gemm_mfma(float* __restrict__ out,
                                                      const ushort* __restrict__ xbase,
                                                      const ushort* __restrict__ wT,
                                                      const float* __restrict__ bias) {
    __shared__ __align__(16) short lsA[128 * 64];
    __shared__ __align__(16) short lsB[128 * 64];

    int b = blockIdx.y;
    int v0 = blockIdx.x * 128;
    int tid = threadIdx.x;
    int lane = tid & 63;
    int w = tid >> 6;
    int mw = w & 1;
    int nw = w >> 1;
    int ln = lane & 15;
    int quad = lane >> 4;

    int srow = tid >> 1;
    int posBase = (tid & 1) * 4;

    floatx4 acc[4][4];
#pragma unroll
    for (int mi = 0; mi < 4; ++mi)
#pragma unroll
        for (int ni = 0; ni < 4; ++ni) acc[mi][ni] = (floatx4){0.f, 0.f, 0.f, 0.f};

    for (int kc = 0; kc < 4; ++kc) {
        __syncthreads();
        // stage A: wT rows (o)
#pragma unroll
        for (int j = 0; j < 4; ++j) {
            int pos = posBase + j;
            int g = pos ^ (srow & 7);
            uint4 val = *reinterpret_cast<const uint4*>(wT + (size_t)srow * 256 + kc * 64 + g * 8);
            *reinterpret_cast<uint4*>(&lsA[(srow * 8 + pos) * 8]) = val;
        }
        // stage B: xk bf16 direct copy
        {
            const ushort* xk = xbase + (size_t)kc * VN * FN;
            int v = v0 + srow;
            bool ok = (v < VN);
            const ushort* src = xk + (size_t)v * FN + b * CINN;
#pragma unroll
            for (int j = 0; j < 4; ++j) {
                int pos = posBase + j;
                int g = pos ^ (srow & 7);
                uint4 val;
                if (ok) val = *reinterpret_cast<const uint4*>(src + g * 8);
                else    val = make_uint4(0u, 0u, 0u, 0u);
                *reinterpret_cast<uint4*>(&lsB[(srow * 8 + pos) * 8]) = val;
            }
        }
        __syncthreads();

#pragma unroll
        for (int s = 0; s < 2; ++s) {
            short8 afr[4], bfr[4];
#pragma unroll
            for (int mi = 0; mi < 4; ++mi) {
                int r = mw * 64 + mi * 16 + ln;
                int pos = (s * 4 + quad) ^ (r & 7);
                afr[mi] = *reinterpret_cast<const short8*>(&lsA[(r * 8 + pos) * 8]);
            }
#pragma unroll
            for (int ni = 0; ni < 4; ++ni) {
                int r = nw * 64 + ni * 16 + ln;
                int pos = (s * 4 + quad) ^ (r & 7);
                bfr[ni] = *reinterpret_cast<const short8*>(&lsB[(r * 8 + pos) * 8]);
            }
#pragma unroll
            for (int mi = 0; mi < 4; ++mi)
#pragma unroll
                for (int ni = 0; ni < 4; ++ni)
                    acc[mi][ni] = __builtin_amdgcn_mfma_f32_16x16x32_bf16(
                        afr[mi], bfr[ni], acc[mi][ni], 0, 0, 0);
        }
    }

#pragma unroll
    for (int mi = 0; mi < 4; ++mi) {
#pragma unroll
        for (int r = 0; r < 4; ++r) {
            int o = mw * 64 + mi * 16 + quad * 4 + r;
            float bv = bias[o];
            size_t obase = (size_t)(b * COUTN + o) * VN;
#pragma unroll
            for (int ni = 0; ni < 4; ++ni) {
                int v = v0 + nw * 64 + ni * 16 + ln;
                if (v < VN) out[obase + v] = acc[mi][ni][r] + bv;
            }
        }
    }
}

// ---------------------------------------------------------------------------
extern "C" void kernel_launch(void* const* d_in, const int* in_sizes, int n_in,
                              void* d_out, int out_size, void* d_ws, size_t ws_size,
                              hipStream_t stream) {
    const float* x        = (const float*)d_in[0];
    const int*   lap_rows = (const int*)d_in[1];
    const int*   lap_cols = (const int*)d_in[2];
    const float* lap_vals = (const float*)d_in[3];
    const float* weight   = (const float*)d_in[4];
    const float* bias     = (const float*)d_in[5];
    float* out = (float*)d_out;

    char* ws = (char*)d_ws;
    ushort* x0 = (ushort*)ws;                        // 4 x (V,256) bf16, contiguous
    ushort* x1 = x0 + (size_t)VN * FN;
    ushort* x2 = x1 + (size_t)VN * FN;
    ushort* x3 = x2 + (size_t)VN * FN;
    size_t xbytes = (size_t)4 * VN * FN * sizeof(ushort);
    int* row_ptr = (int*)(ws + xbytes);              // V+1 ints
    size_t rp_end = xbytes + (size_t)(VN + 1) * sizeof(int);
    rp_end = (rp_end + 15) & ~(size_t)15;            // 16B align
    ushort* wT = (ushort*)(ws + rp_end);             // (128,256) bf16

    setup_fused<<<RP_BLOCKS + WT_BLOCKS + TP_BLOCKS, 256, 0, stream>>>(
        lap_rows, row_ptr, weight, wT, x, x0);
    // x1 = L x0
    spmm_cheb_bf16<<<(VN + 3) / 4, 256, 0, stream>>>(x1, x0, x0, row_ptr, lap_cols, lap_vals, 1.f, 0.f);
    // x2 = 2 L x1 - x0
    spmm_cheb_bf16<<<(VN + 3) / 4, 256, 0, stream>>>(x2, x1, x0, row_ptr, lap_cols, lap_vals, 2.f, -1.f);
    // x3 = 2 L x2 - x1
    spmm_cheb_bf16<<<(VN + 3) / 4, 256, 0, stream>>>(x3, x2, x1, row_ptr, lap_cols, lap_vals, 2.f, -1.f);
    // out = sum_k xk @ Wk + bias  (MFMA)
    cheb_gemm_mfma<<<dim3((VN + 127) / 128, BN), 256, 0, stream>>>(out, x0, wT, bias);
}